// Round 10
// baseline (881.856 us; speedup 1.0000x reference)
//
#include <hip/hip_runtime.h>
#include <hip/hip_bf16.h>

// Fused 2-layer LSTM (H=32) + linear head, MI355X gfx950.
// r10: transposed-gates layout. MFMA: A = W (gate rows, pi-permuted),
// B = input (features/units x batch). D[gate_row][batch]: lane = batch col
// (l&15), rows = gate-units. Row permutation pi chosen so each lane's cell
// outputs ARE its next-step B-frag (units 8g..8g+7 for batch l&15):
// same-layer recurrence entirely in-registers, in-lane. NO per-step barrier.
// WG = 8 batch rows x 2 waves (wave0 = L1, wave1 = L2, trailing 8 steps).
// h1 passes L1->L2 through a 16-slot LDS ring double-buffered by window
// parity; ONE barrier per 8 steps (65 total vs r7's 513).
// Batch cols 8-15 of every MFMA stay exactly zero (x=0 -> h=0 fixpoint).
// Gates via mfma_f32_16x16x32_bf16, hi/lo bf16 split (~fp32 exact).

#define T_LEN 512
#define D_IN  28
#define DWIN  8
#define NSLOT 16  // 2*DWIN

typedef __attribute__((ext_vector_type(8))) short short8;   // 8 x bf16
typedef __attribute__((ext_vector_type(4))) float f32x4;
typedef __attribute__((ext_vector_type(4))) unsigned int u32x4;

#define K_SIG 1.4426950408889634f   // 1/ln2
#define K_TANH 2.8853900817779268f  // 2/ln2

__device__ __forceinline__ void split_bf16(float x, short& hi, short& lo) {
  unsigned u = __float_as_uint(x);
  hi = (short)(u >> 16);
  float hf_ = __uint_as_float(u & 0xFFFF0000u);
  float lf = x - hf_;  // exact
  lo = (short)(__float_as_uint(lf) >> 16);
}

// dword = (top16(f1) << 16) | top16(f0), one v_perm_b32.
__device__ __forceinline__ unsigned pk_hi16(float f1, float f0) {
  return __builtin_amdgcn_perm(__float_as_uint(f1), __float_as_uint(f0),
                               0x07060302u);
}
__device__ __forceinline__ float trunc_bf(float f) {
  return __uint_as_float(__float_as_uint(f) & 0xFFFF0000u);
}

// Barrier draining LDS ops only (global x prefetch stays in flight).
__device__ __forceinline__ void lds_barrier() {
  asm volatile("s_waitcnt lgkmcnt(0)\n\ts_barrier" ::: "memory");
}

#define MFMA(a, b, c) __builtin_amdgcn_mfma_f32_16x16x32_bf16(a, b, c, 0, 0, 0)

// A-frag loader with the unit-interleaving gate-row permutation pi:
// tile t (gate G = t>>1, half = t&1), tile-row m -> W row
//   32*G + 8*(m>>2) + 4*half + (m&3).
// Lane l holds tile-row m = l&15, k = (l>>4)*8 .. +8 (zero past kval).
// => C-frag reg r of lane (b=l&15, g=l>>4), tile t = gate G, unit
//    8g + 4*half + r, batch b.
__device__ __forceinline__ void load_wtileA(const float* __restrict__ W,
                                            int ldk, int kval, int t, int lane,
                                            short8& hi, short8& lo) {
  int m = lane & 15;
  int row = 32 * (t >> 1) + 8 * (m >> 2) + 4 * (t & 1) + (m & 3);
  int kb = (lane >> 4) * 8;
  const float* p = W + row * ldk + kb;
#pragma unroll
  for (int i = 0; i < 8; ++i) {
    float v = (kb + i < kval) ? p[i] : 0.0f;
    short h_, l_;
    split_bf16(v, h_, l_);
    hi[i] = h_; lo[i] = l_;
  }
}

// Pack 8 f32 -> B-frag hi/lo dwords (element i = k-offset i in the frag).
__device__ __forceinline__ void pack8f(const float* v, u32x4& H, u32x4& L) {
#pragma unroll
  for (int d = 0; d < 4; ++d) H[d] = pk_hi16(v[2 * d + 1], v[2 * d]);
  float r[8];
#pragma unroll
  for (int i = 0; i < 8; ++i) r[i] = v[i] - trunc_bf(v[i]);
#pragma unroll
  for (int d = 0; d < 4; ++d) L[d] = pk_hi16(r[2 * d + 1], r[2 * d]);
}

// 48 MFMAs: acc[t] = Wx[t]@in + Wh[t]@hb, hi/lo 3-term each, interleaved
// in rounds of 8 independent ops (same-acc reuse distance 8).
__device__ __forceinline__ void gates48(f32x4* acc,
    const short8* WxH, const short8* WxL, const short8* WhH, const short8* WhL,
    short8 inH, short8 inL, short8 hH, short8 hL) {
#pragma unroll
  for (int t = 0; t < 8; ++t) {
    f32x4 z = {0.f, 0.f, 0.f, 0.f};
    acc[t] = MFMA(WxH[t], inH, z);
  }
#pragma unroll
  for (int t = 0; t < 8; ++t) acc[t] = MFMA(WxH[t], inL, acc[t]);
#pragma unroll
  for (int t = 0; t < 8; ++t) acc[t] = MFMA(WxL[t], inH, acc[t]);
#pragma unroll
  for (int t = 0; t < 8; ++t) acc[t] = MFMA(WhH[t], hH, acc[t]);
#pragma unroll
  for (int t = 0; t < 8; ++t) acc[t] = MFMA(WhH[t], hL, acc[t]);
#pragma unroll
  for (int t = 0; t < 8; ++t) acc[t] = MFMA(WhL[t], hH, acc[t]);
}

// Cell update for the lane's 8 units (gate G at acc[2G + (j>>2)][j&3]).
// Paired rcps: 40 exp2 + 8 rcp = 48 trans.
__device__ __forceinline__ void cell8(const f32x4* acc, float* c, float* h) {
  float ei[8], ef[8], eg[8], eo[8];
#pragma unroll
  for (int j = 0; j < 8; ++j) {
    int hb = j >> 2, r = j & 3;
    ei[j] = __builtin_amdgcn_exp2f(acc[0 + hb][r] * -K_SIG);
    ef[j] = __builtin_amdgcn_exp2f(acc[2 + hb][r] * -K_SIG);
    eg[j] = __builtin_amdgcn_exp2f(acc[4 + hb][r] * K_TANH);
    eo[j] = __builtin_amdgcn_exp2f(acc[6 + hb][r] * -K_SIG);
  }
  float num[8], D[8], cn[8];
#pragma unroll
  for (int j = 0; j < 8; ++j) {
    float pig = (1.0f + ei[j]) * (1.0f + eg[j]);
    num[j] = c[j] * pig + (eg[j] - 1.0f) * (1.0f + ef[j]);
    D[j] = pig * (1.0f + ef[j]);
  }
#pragma unroll
  for (int p = 0; p < 4; ++p) {
    float R = __builtin_amdgcn_rcpf(D[2 * p] * D[2 * p + 1]);
    cn[2 * p] = num[2 * p] * D[2 * p + 1] * R;
    cn[2 * p + 1] = num[2 * p + 1] * D[2 * p] * R;
  }
  float ec[8], E[8];
#pragma unroll
  for (int j = 0; j < 8; ++j) ec[j] = __builtin_amdgcn_exp2f(cn[j] * K_TANH);
#pragma unroll
  for (int j = 0; j < 8; ++j) E[j] = (1.0f + eo[j]) * (1.0f + ec[j]);
#pragma unroll
  for (int p = 0; p < 4; ++p) {
    float S = __builtin_amdgcn_rcpf(E[2 * p] * E[2 * p + 1]);
    h[2 * p] = (ec[2 * p] - 1.0f) * E[2 * p + 1] * S;
    h[2 * p + 1] = (ec[2 * p + 1] - 1.0f) * E[2 * p] * S;
  }
#pragma unroll
  for (int j = 0; j < 8; ++j) c[j] = cn[j];
}

// One L1 step: consume x B-frag regs, refill for s+2, recur in-lane,
// publish h1 B-frag to ring slot (4 x ds_write_b64).
__device__ __forceinline__ void l1_step(
    float4& XA0, float4& XA1, const float* __restrict__ ld, bool pv0, bool pv1,
    const short8* WxH, const short8* WxL, const short8* WhH, const short8* WhL,
    u32x4& hbH, u32x4& hbL, float* c, float* h,
    unsigned (*slot)[64][2], int lane) {
  float xv[8] = {XA0.x, XA0.y, XA0.z, XA0.w, XA1.x, XA1.y, XA1.z, XA1.w};
  u32x4 xH, xL;
  pack8f(xv, xH, xL);
  XA0 = pv0 ? *(const float4*)(ld) : make_float4(0, 0, 0, 0);
  XA1 = pv1 ? *(const float4*)(ld + 4) : make_float4(0, 0, 0, 0);
  f32x4 acc[8];
  gates48(acc, WxH, WxL, WhH, WhL,
          __builtin_bit_cast(short8, xH), __builtin_bit_cast(short8, xL),
          __builtin_bit_cast(short8, hbH), __builtin_bit_cast(short8, hbL));
  cell8(acc, c, h);
  pack8f(h, hbH, hbL);
  *(uint2*)&slot[0][lane][0] = make_uint2(hbH[0], hbH[1]);
  *(uint2*)&slot[1][lane][0] = make_uint2(hbH[2], hbH[3]);
  *(uint2*)&slot[2][lane][0] = make_uint2(hbL[0], hbL[1]);
  *(uint2*)&slot[3][lane][0] = make_uint2(hbL[2], hbL[3]);
}

// One L2 step: read h1 B-frag from ring slot, recur in-lane.
__device__ __forceinline__ void l2_step(
    const short8* WxH, const short8* WxL, const short8* WhH, const short8* WhL,
    u32x4& hbH, u32x4& hbL, float* c, float* h,
    const unsigned (*slot)[64][2], int lane) {
  uint2 r0 = *(const uint2*)&slot[0][lane][0];
  uint2 r1 = *(const uint2*)&slot[1][lane][0];
  uint2 r2 = *(const uint2*)&slot[2][lane][0];
  uint2 r3 = *(const uint2*)&slot[3][lane][0];
  u32x4 aH = {r0.x, r0.y, r1.x, r1.y};
  u32x4 aL = {r2.x, r2.y, r3.x, r3.y};
  f32x4 acc[8];
  gates48(acc, WxH, WxL, WhH, WhL,
          __builtin_bit_cast(short8, aH), __builtin_bit_cast(short8, aL),
          __builtin_bit_cast(short8, hbH), __builtin_bit_cast(short8, hbL));
  cell8(acc, c, h);
  pack8f(h, hbH, hbL);
}

__global__ __launch_bounds__(128, 1) void lstm2_gt(
    const float* __restrict__ x, const float* __restrict__ wih0,
    const float* __restrict__ whh0, const float* __restrict__ wih1,
    const float* __restrict__ whh1, const float* __restrict__ wout,
    const float* __restrict__ bout, float* __restrict__ out) {
  __shared__ unsigned ring[NSLOT][4][64][2];  // h1 B-frags, b64 granules
  __shared__ float hf[8][33];

  const int tid = threadIdx.x;
  const int lane = tid & 63;
  const int wv = tid >> 6;   // 0 = L1 wave, 1 = L2 wave
  const int b = lane & 15;   // batch col (valid < 8)
  const int g = lane >> 4;   // k-group: units/features 8g..8g+7
  const int b0 = blockIdx.x * 8;

  // ---- weights as pi-permuted A-frags (hi/lo), one layer per wave ----
  const float* Wx = wv ? wih1 : wih0;
  const float* Wh = wv ? whh1 : whh0;
  const int ldk = wv ? 32 : 28;
  short8 WxH[8], WxL[8], WhH[8], WhL[8];
#pragma unroll
  for (int t = 0; t < 8; ++t) {
    load_wtileA(Wx, ldk, ldk, t, lane, WxH[t], WxL[t]);
    load_wtileA(Wh, 32, 32, t, lane, WhH[t], WhL[t]);
  }

  float c[8], h[8];
#pragma unroll
  for (int j = 0; j < 8; ++j) { c[j] = 0.f; h[j] = 0.f; }
  u32x4 hbH = {0, 0, 0, 0}, hbL = {0, 0, 0, 0};  // own-h B-frag

  // L1 x-prefetch ring (2-step flight): X0 = even steps, X1 = odd steps.
  const bool pv0 = (b < 8);
  const bool pv1 = (b < 8) && (g < 3);  // features 28..31 are pad
  const float* xrow = x + (size_t)(b0 + (b & 7)) * T_LEN * D_IN + 8 * g;
  float4 X00 = make_float4(0, 0, 0, 0), X01 = X00, X10 = X00, X11 = X00;
  if (wv == 0) {
    if (pv0) X00 = *(const float4*)(xrow);
    if (pv1) X01 = *(const float4*)(xrow + 4);
    if (pv0) X10 = *(const float4*)(xrow + D_IN);
    if (pv1) X11 = *(const float4*)(xrow + D_IN + 4);
  }

  // ---- main loop: 65 windows of 8 steps, ONE barrier per window ----
  // Window w: L1 runs steps [w*8, w*8+8) writing ring slots (w&1)*8+d;
  //           L2 runs steps [(w-1)*8, w*8) reading slots ((w&1)^1)*8+d
  //           (written in window w-1, made visible by its barrier).
  // L1's window-w writes reuse slots L2 read in window w-1: ordered by
  // the same barrier. x global loads cross barriers by design.
#pragma unroll 1
  for (int w = 0; w < T_LEN / DWIN + 1; ++w) {
    if (wv == 0) {
      if (w < T_LEN / DWIN) {
        const int sb = w * DWIN;
        const int slotb = (w & 1) * DWIN;
#pragma unroll 1
        for (int dp = 0; dp < DWIN / 2; ++dp) {
          int s0 = sb + 2 * dp;
          int t2 = (s0 + 2 < T_LEN) ? s0 + 2 : T_LEN - 1;
          l1_step(X00, X01, xrow + (size_t)t2 * D_IN, pv0, pv1,
                  WxH, WxL, WhH, WhL, hbH, hbL, c, h,
                  ring[slotb + 2 * dp], lane);
          int t3 = (s0 + 3 < T_LEN) ? s0 + 3 : T_LEN - 1;
          l1_step(X10, X11, xrow + (size_t)t3 * D_IN, pv0, pv1,
                  WxH, WxL, WhH, WhL, hbH, hbL, c, h,
                  ring[slotb + 2 * dp + 1], lane);
        }
      }
    } else {
      if (w >= 1) {
        const int slotb = ((w & 1) ^ 1) * DWIN;
#pragma unroll 2
        for (int d = 0; d < DWIN; ++d) {
          l2_step(WxH, WxL, WhH, WhL, hbH, hbL, c, h,
                  ring[slotb + d], lane);
        }
      }
    }
    lds_barrier();
  }

  // ---- epilogue: L2 wave holds h2(511); out = h2 @ wout^T + bout ----
  if (wv == 1 && b < 8) {
#pragma unroll
    for (int j = 0; j < 8; ++j) hf[b][8 * g + j] = h[j];
  }
  __syncthreads();

  for (int jj = tid; jj < 80; jj += 128) {
    int row = jj / 10, col = jj % 10;
    float s = bout[col];
#pragma unroll
    for (int u = 0; u < 32; ++u) s += hf[row][u] * wout[col * 32 + u];
    out[(size_t)(b0 + row) * 10 + col] = s;
  }
}

extern "C" void kernel_launch(void* const* d_in, const int* in_sizes, int n_in,
                              void* d_out, int out_size, void* d_ws, size_t ws_size,
                              hipStream_t stream) {
  const float* x = (const float*)d_in[0];
  const float* wih0 = (const float*)d_in[1];
  const float* whh0 = (const float*)d_in[2];
  const float* wih1 = (const float*)d_in[3];
  const float* whh1 = (const float*)d_in[4];
  const float* wout = (const float*)d_in[5];
  const float* bout = (const float*)d_in[6];
  float* out = (float*)d_out;
  lstm2_gt<<<512, 128, 0, stream>>>(x, wih0, whh0, wih1, whh1, wout, bout, out);
}

// Round 11
// 404.845 us; speedup vs baseline: 2.1783x; 2.1783x over previous
//
#include <hip/hip_runtime.h>
#include <hip/hip_bf16.h>

// Fused 2-layer LSTM (H=32) + linear head, MI355X gfx950.
// r11 = r7 skeleton at 8 batch rows/WG with M-DUPLICATION for 2 waves/SIMD.
// 512 WGs x 4 waves = 2048 waves (r7: 1024 = 1/SIMD, ~35% idle).
// MFMA M rows 8-15 duplicate batch 0-7 (A-frag reads row&7): lanes 32-63
// hold copies of the gate values, so elementwise splits by lane half
// (lgrp<2 -> C-rows 0,1; lgrp>=2 -> C-rows 2,3): every lane owns exactly
// 2 real cells -> 12 trans/wave, no masked-lane waste (r3's mistake).
// Per-SIMD issue ~= r7 for the same useful work; two independent WGs per
// CU now hide each other's latency + barrier convoy.
// Waves 0-1 = L1 @ s, waves 2-3 = L2 @ s-1; one lgkm-only barrier/step;
// static x-prefetch ring (2-step flight, r7's fix).
// Gates via mfma_f32_16x16x32_bf16 with hi/lo bf16 split (~fp32 exact).

#define T_LEN 512
#define D_IN  28

typedef __attribute__((ext_vector_type(8))) short short8;   // 8 x bf16
typedef __attribute__((ext_vector_type(4))) float f32x4;
typedef __attribute__((ext_vector_type(4))) unsigned int u32x4;

#define K_SIG 1.4426950408889634f   // 1/ln2
#define K_TANH 2.8853900817779268f  // 2/ln2

// hi = bf16 truncation of x, lo = bf16 of exact residual (x - hi).
__device__ __forceinline__ void split_bf16(float x, short& hi, short& lo) {
  unsigned u = __float_as_uint(x);
  hi = (short)(u >> 16);
  float hf_ = __uint_as_float(u & 0xFFFF0000u);
  float lf = x - hf_;  // exact
  lo = (short)(__float_as_uint(lf) >> 16);
}

// dword = (top16(f1) << 16) | top16(f0), one v_perm_b32.
__device__ __forceinline__ unsigned pk_hi16(float f1, float f0) {
  return __builtin_amdgcn_perm(__float_as_uint(f1), __float_as_uint(f0),
                               0x07060302u);
}
__device__ __forceinline__ float trunc_bf(float f) {
  return __uint_as_float(__float_as_uint(f) & 0xFFFF0000u);
}

// Barrier that drains LDS ops only (x prefetch stays in flight).
__device__ __forceinline__ void lds_barrier() {
  asm volatile("s_waitcnt lgkmcnt(0)\n\ts_barrier" ::: "memory");
}

// B-operand tile (K=32 x N=16) of W (row-major G x ldk), gate rows
// n*16..n*16+15, k zero-padded past kval. Lane l: col=l&15, k=(l>>4)*8..+8.
__device__ __forceinline__ void load_wtile(const float* __restrict__ W, int ldk,
                                           int kval, int n, int lane,
                                           short8& hi, short8& lo) {
  int row = n * 16 + (lane & 15);
  int kb = (lane >> 4) * 8;
  const float* p = W + row * ldk + kb;
#pragma unroll
  for (int i = 0; i < 8; ++i) {
    float v = (kb + i < kval) ? p[i] : 0.0f;
    short h, l;
    split_bf16(v, h, l);
    hi[i] = h; lo[i] = l;
  }
}

#define MFMA(a, b, c) __builtin_amdgcn_mfma_f32_16x16x32_bf16(a, b, c, 0, 0, 0)

// Pack 8 floats (A0,A1) into hi/lo bf16 A-frags via v_perm.
__device__ __forceinline__ void pack_xfrag(const float4& A0, const float4& A1,
                                           short8& xh, short8& xl) {
  u32x4 xhu, xlu;
  xhu[0] = pk_hi16(A0.y, A0.x);
  xhu[1] = pk_hi16(A0.w, A0.z);
  xhu[2] = pk_hi16(A1.y, A1.x);
  xhu[3] = pk_hi16(A1.w, A1.z);
  float l0 = A0.x - trunc_bf(A0.x), l1 = A0.y - trunc_bf(A0.y);
  float l2 = A0.z - trunc_bf(A0.z), l3 = A0.w - trunc_bf(A0.w);
  float l4 = A1.x - trunc_bf(A1.x), l5 = A1.y - trunc_bf(A1.y);
  float l6 = A1.z - trunc_bf(A1.z), l7 = A1.w - trunc_bf(A1.w);
  xlu[0] = pk_hi16(l1, l0);
  xlu[1] = pk_hi16(l3, l2);
  xlu[2] = pk_hi16(l5, l4);
  xlu[3] = pk_hi16(l7, l6);
  xh = __builtin_bit_cast(short8, xhu);
  xl = __builtin_bit_cast(short8, xlu);
}

// 24 MFMAs interleaved across the 4 gate accumulators (same-acc reuse
// distance 4 => no dependent-issue stall).
__device__ __forceinline__ void gate_mfma(f32x4* acc, short8 ah, short8 al,
                                          const short8* Bh, const short8* Bl,
                                          short8 ch, short8 cl,
                                          const short8* Dh, const short8* Dl) {
#pragma unroll
  for (int tt = 0; tt < 4; ++tt) {
    f32x4 z = {0.f, 0.f, 0.f, 0.f};
    acc[tt] = MFMA(ah, Bh[tt], z);
  }
#pragma unroll
  for (int tt = 0; tt < 4; ++tt) acc[tt] = MFMA(al, Bh[tt], acc[tt]);
#pragma unroll
  for (int tt = 0; tt < 4; ++tt) acc[tt] = MFMA(ah, Bl[tt], acc[tt]);
#pragma unroll
  for (int tt = 0; tt < 4; ++tt) acc[tt] = MFMA(ch, Dh[tt], acc[tt]);
#pragma unroll
  for (int tt = 0; tt < 4; ++tt) acc[tt] = MFMA(cl, Dh[tt], acc[tt]);
#pragma unroll
  for (int tt = 0; tt < 4; ++tt) acc[tt] = MFMA(ch, Dl[tt], acc[tt]);
}

// Cell update for this lane's 2 cells. Gate j value = acc[tt][r0+j] where
// r0 = hi2 ? 2 : 0 (compile-time extracts selected by cndmask, no scratch).
// Paired rcps: 10 exp2 + 2 rcp = 12 trans.
__device__ __forceinline__ void cell2(const f32x4* acc, bool hi2,
                                      float* c, float* h) {
  float g0[2], g1[2], g2[2], g3[2];
#pragma unroll
  for (int j = 0; j < 2; ++j) {
    g0[j] = hi2 ? acc[0][2 + j] : acc[0][j];
    g1[j] = hi2 ? acc[1][2 + j] : acc[1][j];
    g2[j] = hi2 ? acc[2][2 + j] : acc[2][j];
    g3[j] = hi2 ? acc[3][2 + j] : acc[3][j];
  }
  float ei[2], ef[2], eg[2], eo[2];
#pragma unroll
  for (int j = 0; j < 2; ++j) {
    ei[j] = __builtin_amdgcn_exp2f(g0[j] * -K_SIG);
    ef[j] = __builtin_amdgcn_exp2f(g1[j] * -K_SIG);
    eg[j] = __builtin_amdgcn_exp2f(g2[j] * K_TANH);
    eo[j] = __builtin_amdgcn_exp2f(g3[j] * -K_SIG);
  }
  float num[2], D[2];
#pragma unroll
  for (int j = 0; j < 2; ++j) {
    float pig = (1.0f + ei[j]) * (1.0f + eg[j]);
    num[j] = c[j] * pig + (eg[j] - 1.0f) * (1.0f + ef[j]);
    D[j] = pig * (1.0f + ef[j]);
  }
  float R = __builtin_amdgcn_rcpf(D[0] * D[1]);
  float cn0 = num[0] * D[1] * R;
  float cn1 = num[1] * D[0] * R;
  float ec0 = __builtin_amdgcn_exp2f(cn0 * K_TANH);
  float ec1 = __builtin_amdgcn_exp2f(cn1 * K_TANH);
  float E0 = (1.0f + eo[0]) * (1.0f + ec0);
  float E1 = (1.0f + eo[1]) * (1.0f + ec1);
  float S = __builtin_amdgcn_rcpf(E0 * E1);
  c[0] = cn0; h[0] = (ec0 - 1.0f) * E1 * S;
  c[1] = cn1; h[1] = (ec1 - 1.0f) * E0 * S;
}

// Store this lane's 2 cells (hi/lo bf16) to rows (4*lgrp + r0 + j) & 7.
__device__ __forceinline__ void store_h2cells(short (*hb)[8][40], const float* h,
                                              int lgrp, bool hi2, int uu) {
#pragma unroll
  for (int j = 0; j < 2; ++j) {
    short hh_, ll_;
    split_bf16(h[j], hh_, ll_);
    int bj = (4 * lgrp + (hi2 ? 2 : 0) + j) & 7;
    hb[0][bj][uu] = hh_;
    hb[1][bj][uu] = ll_;
  }
}

// One L1 step at compile-time write-parity P.
template <int P>
__device__ __forceinline__ void l1_half(
    float4& A0, float4& A1, const float* __restrict__ ld,
    const short8* Wxh, const short8* Wxl, const short8* Whh_, const short8* Whl,
    short (*h1)[2][8][40], float* c, float* h,
    int brow, int lgrp, bool hi2, int kb, int uu) {
  constexpr int Q = P ^ 1;
  short8 ph = *(const short8*)&h1[Q][0][brow][kb];
  short8 pl = *(const short8*)&h1[Q][1][brow][kb];

  short8 xh, xl;
  pack_xfrag(A0, A1, xh, xl);
  // refill ring slot for step s+2 (in flight across 2 steps)
  A0 = *(const float4*)(ld);
  if (lgrp < 3) A1 = *(const float4*)(ld + 4);

  f32x4 acc[4];
  gate_mfma(acc, xh, xl, Wxh, Wxl, ph, pl, Whh_, Whl);
  cell2(acc, hi2, c, h);
  store_h2cells(h1[P], h, lgrp, hi2, uu);
}

// One L2 step at compile-time write-parity P.
template <int P>
__device__ __forceinline__ void l2_half(
    const short8* Wxh, const short8* Wxl, const short8* Whh_, const short8* Whl,
    short (*h1)[2][8][40], short (*h2)[2][8][40], float* c, float* h,
    int brow, int lgrp, bool hi2, int kb, int uu, bool writeout) {
  constexpr int Q = P ^ 1;
  short8 ah = *(const short8*)&h1[Q][0][brow][kb];
  short8 al = *(const short8*)&h1[Q][1][brow][kb];
  short8 ph = *(const short8*)&h2[Q][0][brow][kb];
  short8 pl = *(const short8*)&h2[Q][1][brow][kb];
  f32x4 acc[4];
  gate_mfma(acc, ah, al, Wxh, Wxl, ph, pl, Whh_, Whl);
  cell2(acc, hi2, c, h);
  if (writeout) store_h2cells(h2[P], h, lgrp, hi2, uu);
}

__global__ __launch_bounds__(256, 2) void lstm2_pipe(
    const float* __restrict__ x, const float* __restrict__ wih0,
    const float* __restrict__ whh0, const float* __restrict__ wih1,
    const float* __restrict__ whh1, const float* __restrict__ wout,
    const float* __restrict__ bout, float* __restrict__ out) {
  __shared__ short h1buf[2][2][8][40];  // [parity][hi/lo][brow][unit pad 40]
  __shared__ short h2buf[2][2][8][40];
  __shared__ float hf[8][33];

  const int tid = threadIdx.x;
  const int lane = tid & 63;
  const int wid = tid >> 6;    // 0..3
  const int layer = wid >> 1;  // 0 => L1 waves, 1 => L2 waves
  const int w01 = wid & 1;     // unit-half within the layer
  const int b0 = blockIdx.x * 8;

  for (int i = tid; i < 2 * 2 * 8 * 40; i += 256) {
    ((short*)h1buf)[i] = 0;
    ((short*)h2buf)[i] = 0;
  }

  const int lrow = lane & 15;   // A-frag row (rows 8-15 duplicate 0-7)
  const int brow = lrow & 7;    // real batch row
  const int lgrp = lane >> 4;   // 0..3
  const bool hi2 = (lgrp >= 2); // which C-row pair this lane finishes
  const int kb = lgrp * 8;
  const int uu = lrow + 16 * w01;  // unit owned in elementwise phase

  // ---- this wave's layer weights in VGPRs (hi/lo bf16) ----
  const float* Wih = layer ? wih1 : wih0;
  const float* Whh = layer ? whh1 : whh0;
  const int ldk = layer ? 32 : 28;

  short8 Wxh[4], Wxl[4], Whh_[4], Whl[4];
#pragma unroll
  for (int tt = 0; tt < 4; ++tt) {
    int n = tt * 2 + w01;
    load_wtile(Wih, ldk, ldk, n, lane, Wxh[tt], Wxl[tt]);
    load_wtile(Whh, 32, 32, n, lane, Whh_[tt], Whl[tt]);
  }

  float c[2] = {0, 0}, h[2] = {0, 0};

  const float* xrow = x + ((size_t)(b0 + brow)) * T_LEN * D_IN + kb;

  // static 2-deep x ring: X0 = even steps, X1 = odd steps
  float4 X0A0 = make_float4(0, 0, 0, 0), X0A1 = make_float4(0, 0, 0, 0);
  float4 X1A0 = make_float4(0, 0, 0, 0), X1A1 = make_float4(0, 0, 0, 0);
  if (layer == 0) {
    X0A0 = *(const float4*)(xrow);
    if (lgrp < 3) X0A1 = *(const float4*)(xrow + 4);
    X1A0 = *(const float4*)(xrow + D_IN);
    if (lgrp < 3) X1A1 = *(const float4*)(xrow + D_IN + 4);
  }

  __syncthreads();  // LDS zero-init visible

  for (int s = 0; s < T_LEN; s += 2) {
    // ---- half A: step s, parity 0 ----
    {
      int t2 = s + 2 < T_LEN ? s + 2 : T_LEN - 1;
      const float* ld = xrow + (size_t)t2 * D_IN;
      if (layer == 0) {
        l1_half<0>(X0A0, X0A1, ld, Wxh, Wxl, Whh_, Whl, h1buf, c, h,
                   brow, lgrp, hi2, kb, uu);
      } else if (s > 0) {
        l2_half<0>(Wxh, Wxl, Whh_, Whl, h1buf, h2buf, c, h,
                   brow, lgrp, hi2, kb, uu, true);
      }
      lds_barrier();
    }
    // ---- half B: step s+1, parity 1 ----
    {
      int t3 = s + 3 < T_LEN ? s + 3 : T_LEN - 1;
      const float* ld = xrow + (size_t)t3 * D_IN;
      if (layer == 0) {
        l1_half<1>(X1A0, X1A1, ld, Wxh, Wxl, Whh_, Whl, h1buf, c, h,
                   brow, lgrp, hi2, kb, uu);
      } else {
        l2_half<1>(Wxh, Wxl, Whh_, Whl, h1buf, h2buf, c, h,
                   brow, lgrp, hi2, kb, uu, true);
      }
      lds_barrier();
    }
    // Hazards: step s reads parity q=(s&1)^1, writes p=s&1; step s+1's
    // writes to q are ordered after this step's reads by the barrier.
    // x loads cross barriers (consumed 2 steps later).
  }

  // ---- tail: step 512, parity 0 — L2 computes h2(511), kept in regs ----
  if (layer == 1) {
    l2_half<0>(Wxh, Wxl, Whh_, Whl, h1buf, h2buf, c, h,
               brow, lgrp, hi2, kb, uu, false);
#pragma unroll
    for (int j = 0; j < 2; ++j) {
      int bj = (4 * lgrp + (hi2 ? 2 : 0) + j) & 7;
      hf[bj][uu] = h[j];
    }
  }
  __syncthreads();

  // ---- epilogue: out = h2(T-1) @ wout^T + bout ----
  for (int j = tid; j < 80; j += 256) {
    int row = j / 10, col = j % 10;
    float s = bout[col];
#pragma unroll
    for (int u = 0; u < 32; ++u) s += hf[row][u] * wout[col * 32 + u];
    out[(size_t)(b0 + row) * 10 + col] = s;
  }
}

extern "C" void kernel_launch(void* const* d_in, const int* in_sizes, int n_in,
                              void* d_out, int out_size, void* d_ws, size_t ws_size,
                              hipStream_t stream) {
  const float* x = (const float*)d_in[0];
  const float* wih0 = (const float*)d_in[1];
  const float* whh0 = (const float*)d_in[2];
  const float* wih1 = (const float*)d_in[3];
  const float* whh1 = (const float*)d_in[4];
  const float* wout = (const float*)d_in[5];
  const float* bout = (const float*)d_in[6];
  float* out = (float*)d_out;
  lstm2_pipe<<<512, 256, 0, stream>>>(x, wih0, whh0, wih1, whh1, wout, bout, out);
}

// Round 14
// 324.008 us; speedup vs baseline: 2.7217x; 1.2495x over previous
//
#include <hip/hip_runtime.h>
#include <hip/hip_bf16.h>

// Fused 2-layer LSTM (H=32) + linear head, MI355X gfx950.
// r14 = r13 with the h2 pre-issue RACE fixed. r12/r13 failed (identical
// absmax 5.37e-3) because l2's p2h/p2l pre-issue read h2(u) BEFORE the
// barrier, but each lane's h2 A-frag spans units written by the OTHER L2
// wave in the same step -> stale cross-wave data. Fix: p2 reads at the
// top of the compute (post-barrier); only the h1 reads (one barrier old,
// race-free) stay pre-issued. Their latency drains under the first 3
// MFMA rounds, which consume the pre-read a1h/a1l.
// Structure: 256 WGs x 4 waves x 16 batch rows; waves 0-1 = L1 @ WG-step
// s, waves 2-3 = L2 @ time u = s-2 (h1 ring = 4 slots); one lgkm-only
// barrier per step; unroll-4 (compile-time slots); static 2-deep x ring.
// Gates via mfma_f32_16x16x32_bf16 with hi/lo bf16 split (~fp32 exact,
// r7/r9-proven absmax 9.77e-4).

#define T_LEN 512
#define D_IN  28

typedef __attribute__((ext_vector_type(8))) short short8;   // 8 x bf16
typedef __attribute__((ext_vector_type(4))) float f32x4;
typedef __attribute__((ext_vector_type(4))) unsigned int u32x4;

#define K_SIG 1.4426950408889634f   // 1/ln2
#define K_TANH 2.8853900817779268f  // 2/ln2

// hi = bf16 truncation of x, lo = bf16 of exact residual (x - hi).
__device__ __forceinline__ void split_bf16(float x, short& hi, short& lo) {
  unsigned u = __float_as_uint(x);
  hi = (short)(u >> 16);
  float hf_ = __uint_as_float(u & 0xFFFF0000u);
  float lf = x - hf_;  // exact
  lo = (short)(__float_as_uint(lf) >> 16);
}

// dword = (top16(f1) << 16) | top16(f0), one v_perm_b32.
__device__ __forceinline__ unsigned pk_hi16(float f1, float f0) {
  return __builtin_amdgcn_perm(__float_as_uint(f1), __float_as_uint(f0),
                               0x07060302u);
}
__device__ __forceinline__ float trunc_bf(float f) {
  return __uint_as_float(__float_as_uint(f) & 0xFFFF0000u);
}

// Barrier draining LDS ops only (global x prefetch stays in flight;
// pre-issued h1 ds_reads complete here, absorbed by the wait).
__device__ __forceinline__ void lds_barrier() {
  asm volatile("s_waitcnt lgkmcnt(0)\n\ts_barrier" ::: "memory");
}

// B-operand tile (K=32 x N=16) of W (row-major G x ldk), gate rows
// n*16..n*16+15, k zero-padded past kval. Lane l: col=l&15, k=(l>>4)*8..+8.
__device__ __forceinline__ void load_wtile(const float* __restrict__ W, int ldk,
                                           int kval, int n, int lane,
                                           short8& hi, short8& lo) {
  int row = n * 16 + (lane & 15);
  int kb = (lane >> 4) * 8;
  const float* p = W + row * ldk + kb;
#pragma unroll
  for (int i = 0; i < 8; ++i) {
    float v = (kb + i < kval) ? p[i] : 0.0f;
    short h, l;
    split_bf16(v, h, l);
    hi[i] = h; lo[i] = l;
  }
}

#define MFMA(a, b, c) __builtin_amdgcn_mfma_f32_16x16x32_bf16(a, b, c, 0, 0, 0)

// Pack 8 floats (A0,A1) into hi/lo bf16 A-frags via v_perm (~26 VALU).
__device__ __forceinline__ void pack_xfrag(const float4& A0, const float4& A1,
                                           short8& xh, short8& xl) {
  u32x4 xhu, xlu;
  xhu[0] = pk_hi16(A0.y, A0.x);
  xhu[1] = pk_hi16(A0.w, A0.z);
  xhu[2] = pk_hi16(A1.y, A1.x);
  xhu[3] = pk_hi16(A1.w, A1.z);
  float l0 = A0.x - trunc_bf(A0.x), l1 = A0.y - trunc_bf(A0.y);
  float l2 = A0.z - trunc_bf(A0.z), l3 = A0.w - trunc_bf(A0.w);
  float l4 = A1.x - trunc_bf(A1.x), l5 = A1.y - trunc_bf(A1.y);
  float l6 = A1.z - trunc_bf(A1.z), l7 = A1.w - trunc_bf(A1.w);
  xlu[0] = pk_hi16(l1, l0);
  xlu[1] = pk_hi16(l3, l2);
  xlu[2] = pk_hi16(l5, l4);
  xlu[3] = pk_hi16(l7, l6);
  xh = __builtin_bit_cast(short8, xhu);
  xl = __builtin_bit_cast(short8, xlu);
}

// Batched LSTM cell update for 4 C-rows, paired rcps (20 exp2 + 4 rcp).
__device__ __forceinline__ void cell_update(const f32x4* acc, float* c, float* h) {
  float ei[4], ef[4], eg[4], eo[4];
#pragma unroll
  for (int r = 0; r < 4; ++r) {
    ei[r] = __builtin_amdgcn_exp2f(acc[0][r] * -K_SIG);
    ef[r] = __builtin_amdgcn_exp2f(acc[1][r] * -K_SIG);
    eg[r] = __builtin_amdgcn_exp2f(acc[2][r] * K_TANH);
    eo[r] = __builtin_amdgcn_exp2f(acc[3][r] * -K_SIG);
  }
  float num[4], D[4];
#pragma unroll
  for (int r = 0; r < 4; ++r) {
    float pig = (1.0f + ei[r]) * (1.0f + eg[r]);
    num[r] = c[r] * pig + (eg[r] - 1.0f) * (1.0f + ef[r]);
    D[r] = pig * (1.0f + ef[r]);
  }
  float R01 = __builtin_amdgcn_rcpf(D[0] * D[1]);
  float R23 = __builtin_amdgcn_rcpf(D[2] * D[3]);
  float cn[4];
  cn[0] = num[0] * D[1] * R01;
  cn[1] = num[1] * D[0] * R01;
  cn[2] = num[2] * D[3] * R23;
  cn[3] = num[3] * D[2] * R23;
  float ec[4], E[4];
#pragma unroll
  for (int r = 0; r < 4; ++r) ec[r] = __builtin_amdgcn_exp2f(cn[r] * K_TANH);
#pragma unroll
  for (int r = 0; r < 4; ++r) E[r] = (1.0f + eo[r]) * (1.0f + ec[r]);
  float S01 = __builtin_amdgcn_rcpf(E[0] * E[1]);
  float S23 = __builtin_amdgcn_rcpf(E[2] * E[3]);
  c[0] = cn[0]; h[0] = (ec[0] - 1.0f) * E[1] * S01;
  c[1] = cn[1]; h[1] = (ec[1] - 1.0f) * E[0] * S01;
  c[2] = cn[2]; h[2] = (ec[2] - 1.0f) * E[3] * S23;
  c[3] = cn[3]; h[3] = (ec[3] - 1.0f) * E[2] * S23;
}

// ---- L1 step at compile-time slot P (writes h1 slot P, reads slot P-1).
// 24 MFMA: 3 x-rounds + 3 h-rounds, interleaved across 4 accumulators.
template <int P>
__device__ __forceinline__ void l1_half(
    float4& A0, float4& A1, const float* __restrict__ ld,
    const short8* WxH, const short8* WxL, const short8* WhH, const short8* WhL,
    short (*h1)[2][16][40], float* c, float* h,
    int lrow, int lgrp, int kb, int uu) {
  constexpr int Q = (P + 3) & 3;
  // own-previous h1: written by L1 waves at step s-1, visible post-barrier
  short8 ph = *(const short8*)&h1[Q][0][lrow][kb];
  short8 pl = *(const short8*)&h1[Q][1][lrow][kb];

  short8 xh, xl;
  pack_xfrag(A0, A1, xh, xl);
  // refill ring slot for step s+2 (2-step flight, never waited young)
  A0 = *(const float4*)(ld);
  if (lgrp < 3) A1 = *(const float4*)(ld + 4);

  f32x4 acc[4];
#pragma unroll
  for (int tt = 0; tt < 4; ++tt) {
    f32x4 z = {0.f, 0.f, 0.f, 0.f};
    acc[tt] = MFMA(xh, WxH[tt], z);
  }
#pragma unroll
  for (int tt = 0; tt < 4; ++tt) acc[tt] = MFMA(xl, WxH[tt], acc[tt]);
#pragma unroll
  for (int tt = 0; tt < 4; ++tt) acc[tt] = MFMA(xh, WxL[tt], acc[tt]);
#pragma unroll
  for (int tt = 0; tt < 4; ++tt) acc[tt] = MFMA(ph, WhH[tt], acc[tt]);
#pragma unroll
  for (int tt = 0; tt < 4; ++tt) acc[tt] = MFMA(pl, WhH[tt], acc[tt]);
#pragma unroll
  for (int tt = 0; tt < 4; ++tt) acc[tt] = MFMA(ph, WhL[tt], acc[tt]);

  cell_update(acc, c, h);
#pragma unroll
  for (int r = 0; r < 4; ++r) {
    short hh_, ll_;
    split_bf16(h[r], hh_, ll_);
    int row = lgrp * 4 + r;
    h1[P][0][row][uu] = hh_;
    h1[P][1][row][uu] = ll_;
  }
}

// ---- L2 step at compile-time slot P (WG-step s, computes time u = s-2).
// a1h/a1l (h1(u)) were PRE-ISSUED last step (race-free: one barrier old).
// p2h/p2l (h2(u-1)) are read HERE, post-barrier (cross-wave halves of the
// frag were written by the other L2 wave last step -> need the barrier).
// Their ds_read latency drains under the first 3 rounds (a1-only MFMAs).
template <int P>
__device__ __forceinline__ void l2_half(
    short8& a1h, short8& a1l,
    const short8* WxH, const short8* WxL, const short8* WhH, const short8* WhL,
    short (*h1)[2][16][40], short (*h2)[2][16][40], float* c, float* h,
    int lrow, int lgrp, int kb, int uu, bool compute) {
  if (compute) {
    // h2(u-1) lives in parity (P+1)&1; written at step s-1, post-barrier ok
    short8 p2h = *(const short8*)&h2[(P + 1) & 1][0][lrow][kb];
    short8 p2l = *(const short8*)&h2[(P + 1) & 1][1][lrow][kb];
    f32x4 acc[4];
#pragma unroll
    for (int tt = 0; tt < 4; ++tt) {
      f32x4 z = {0.f, 0.f, 0.f, 0.f};
      acc[tt] = MFMA(a1h, WxH[tt], z);
    }
#pragma unroll
    for (int tt = 0; tt < 4; ++tt) acc[tt] = MFMA(a1l, WxH[tt], acc[tt]);
#pragma unroll
    for (int tt = 0; tt < 4; ++tt) acc[tt] = MFMA(a1h, WxL[tt], acc[tt]);
#pragma unroll
    for (int tt = 0; tt < 4; ++tt) acc[tt] = MFMA(p2h, WhH[tt], acc[tt]);
#pragma unroll
    for (int tt = 0; tt < 4; ++tt) acc[tt] = MFMA(p2l, WhH[tt], acc[tt]);
#pragma unroll
    for (int tt = 0; tt < 4; ++tt) acc[tt] = MFMA(p2h, WhL[tt], acc[tt]);

    cell_update(acc, c, h);
#pragma unroll
    for (int r = 0; r < 4; ++r) {
      short hh_, ll_;
      split_bf16(h[r], hh_, ll_);
      int row = lgrp * 4 + r;
      h2[P & 1][0][row][uu] = hh_;
      h2[P & 1][1][row][uu] = ll_;
    }
  }
  // Pre-issue next step's h1(s-1) = slot (P+3)&3: written by L1 at step
  // s-1, made visible by barrier(s-1) which has already passed -> SAFE.
  // (h2 must NOT be pre-issued here: its cross-wave half is only ordered
  // by the upcoming barrier — that was the r12/r13 bug.)
  a1h = *(const short8*)&h1[(P + 3) & 3][0][lrow][kb];
  a1l = *(const short8*)&h1[(P + 3) & 3][1][lrow][kb];
}

__global__ __launch_bounds__(256) void lstm2_pipe(
    const float* __restrict__ x, const float* __restrict__ wih0,
    const float* __restrict__ whh0, const float* __restrict__ wih1,
    const float* __restrict__ whh1, const float* __restrict__ wout,
    const float* __restrict__ bout, float* __restrict__ out) {
  __shared__ short h1buf[4][2][16][40];  // [slot s&3][hi/lo][row][unit pad]
  __shared__ short h2buf[2][2][16][40];  // [parity][hi/lo][row][unit pad]
  __shared__ float hf[16][33];

  const int tid = threadIdx.x;
  const int lane = tid & 63;
  const int wid = tid >> 6;    // 0..3
  const int layer = wid >> 1;  // 0 => L1 waves, 1 => L2 waves
  const int w01 = wid & 1;     // unit-half within the layer
  const int b0 = blockIdx.x * 16;

  for (int i = tid; i < 4 * 2 * 16 * 40; i += 256) ((short*)h1buf)[i] = 0;
  for (int i = tid; i < 2 * 2 * 16 * 40; i += 256) ((short*)h2buf)[i] = 0;

  const int lrow = lane & 15;  // A-frag row / C-frag col
  const int lgrp = lane >> 4;  // 0..3
  const int kb = lgrp * 8;
  const int uu = lrow + 16 * w01;  // unit owned in elementwise phase

  // ---- this wave's layer weights in VGPRs (hi/lo bf16) ----
  const float* Wih = layer ? wih1 : wih0;
  const float* Whh = layer ? whh1 : whh0;
  const int ldk = layer ? 32 : 28;

  short8 WxH[4], WxL[4], WhH[4], WhL[4];
#pragma unroll
  for (int tt = 0; tt < 4; ++tt) {
    int n = tt * 2 + w01;
    load_wtile(Wih, ldk, ldk, n, lane, WxH[tt], WxL[tt]);
    load_wtile(Whh, 32, 32, n, lane, WhH[tt], WhL[tt]);
  }

  float c[4] = {0, 0, 0, 0}, h[4] = {0, 0, 0, 0};

  const float* xrow = x + ((size_t)(b0 + lrow)) * T_LEN * D_IN + kb;

  // static 2-deep x ring: X0 = even WG-steps, X1 = odd WG-steps (L1 only)
  float4 X0A0 = make_float4(0, 0, 0, 0), X0A1 = make_float4(0, 0, 0, 0);
  float4 X1A0 = make_float4(0, 0, 0, 0), X1A1 = make_float4(0, 0, 0, 0);
  if (layer == 0) {
    X0A0 = *(const float4*)(xrow);
    if (lgrp < 3) X0A1 = *(const float4*)(xrow + 4);
    X1A0 = *(const float4*)(xrow + D_IN);
    if (lgrp < 3) X1A1 = *(const float4*)(xrow + D_IN + 4);
  }

  // L2 pre-read registers (start as h1(-1)=0; LDS is zeroed)
  short8 a1h = {0, 0, 0, 0, 0, 0, 0, 0};
  short8 a1l = a1h;

  __syncthreads();  // LDS zero-init visible

  // ---- main loop: WG-steps s=0..515 (L1 active s<512; L2 active
  // 2<=s<514 at time u=s-2). One lgkm-only barrier per step.
#pragma unroll 1
  for (int s = 0; s < 516; s += 4) {
    // P = 0
    if (layer == 0) {
      if (s < T_LEN) {
        int t = (s + 2 < T_LEN) ? s + 2 : T_LEN - 1;
        l1_half<0>(X0A0, X0A1, xrow + (size_t)t * D_IN, WxH, WxL, WhH, WhL,
                   h1buf, c, h, lrow, lgrp, kb, uu);
      }
    } else {
      l2_half<0>(a1h, a1l, WxH, WxL, WhH, WhL, h1buf, h2buf, c, h,
                 lrow, lgrp, kb, uu, (s >= 2) && (s < T_LEN + 2));
    }
    lds_barrier();
    // P = 1
    if (layer == 0) {
      if (s + 1 < T_LEN) {
        int t = (s + 3 < T_LEN) ? s + 3 : T_LEN - 1;
        l1_half<1>(X1A0, X1A1, xrow + (size_t)t * D_IN, WxH, WxL, WhH, WhL,
                   h1buf, c, h, lrow, lgrp, kb, uu);
      }
    } else {
      l2_half<1>(a1h, a1l, WxH, WxL, WhH, WhL, h1buf, h2buf, c, h,
                 lrow, lgrp, kb, uu, (s + 1 >= 2) && (s + 1 < T_LEN + 2));
    }
    lds_barrier();
    // P = 2
    if (layer == 0) {
      if (s + 2 < T_LEN) {
        int t = (s + 4 < T_LEN) ? s + 4 : T_LEN - 1;
        l1_half<2>(X0A0, X0A1, xrow + (size_t)t * D_IN, WxH, WxL, WhH, WhL,
                   h1buf, c, h, lrow, lgrp, kb, uu);
      }
    } else {
      l2_half<2>(a1h, a1l, WxH, WxL, WhH, WhL, h1buf, h2buf, c, h,
                 lrow, lgrp, kb, uu, (s + 2 >= 2) && (s + 2 < T_LEN + 2));
    }
    lds_barrier();
    // P = 3
    if (layer == 0) {
      if (s + 3 < T_LEN) {
        int t = (s + 5 < T_LEN) ? s + 5 : T_LEN - 1;
        l1_half<3>(X1A0, X1A1, xrow + (size_t)t * D_IN, WxH, WxL, WhH, WhL,
                   h1buf, c, h, lrow, lgrp, kb, uu);
      }
    } else {
      l2_half<3>(a1h, a1l, WxH, WxL, WhH, WhL, h1buf, h2buf, c, h,
                 lrow, lgrp, kb, uu, (s + 3 >= 2) && (s + 3 < T_LEN + 2));
    }
    lds_barrier();
  }
  // Hazard audit: h1 slot P written at WG-step s (pre-barrier s); readers:
  // L1 at step s+1 (post-barrier s) and L2's pre-issue during step s+1
  // (post-barrier s); overwritten at step s+4 (post-barrier s+3 > both).
  // h2 parity written step s pre-barrier; read step s+1 post-barrier;
  // overwritten step s+2 (after barrier s+1 > the read). x loads cross
  // barriers by design (consumed 2 WG-steps later).

  // ---- epilogue: L2 waves hold h2(511); out = h2 @ wout^T + bout ----
  if (layer == 1) {
#pragma unroll
    for (int r = 0; r < 4; ++r) hf[lgrp * 4 + r][uu] = h[r];
  }
  __syncthreads();

  for (int j = tid; j < 160; j += 256) {
    int row = j / 10, col = j % 10;
    float s = bout[col];
#pragma unroll
    for (int u = 0; u < 32; ++u) s += hf[row][u] * wout[col * 32 + u];
    out[(size_t)(b0 + row) * 10 + col] = s;
  }
}

extern "C" void kernel_launch(void* const* d_in, const int* in_sizes, int n_in,
                              void* d_out, int out_size, void* d_ws, size_t ws_size,
                              hipStream_t stream) {
  const float* x = (const float*)d_in[0];
  const float* wih0 = (const float*)d_in[1];
  const float* whh0 = (const float*)d_in[2];
  const float* wih1 = (const float*)d_in[3];
  const float* whh1 = (const float*)d_in[4];
  const float* wout = (const float*)d_in[5];
  const float* bout = (const float*)d_in[6];
  float* out = (float*)d_out;
  lstm2_pipe<<<256, 256, 0, stream>>>(x, wih0, whh0, wih1, whh1, wout, bout, out);
}